// Round 9
// baseline (609.219 us; speedup 1.0000x reference)
//
#include <hip/hip_runtime.h>
#include <cstdint>
#include <cstddef>

typedef unsigned short u16;
typedef unsigned int u32;
typedef __attribute__((ext_vector_type(8))) short short8;
typedef __attribute__((ext_vector_type(4))) float f32x4;

static constexpr int IN_F = 128;
static constexpr int HID  = 256;
#define EPS_BN 1e-5f
#define EPS_L2 1e-12f

__device__ inline float bf2f(u16 a){ return __uint_as_float((unsigned)a << 16); }
__device__ inline u16 f2bf_rne(float v){
    unsigned u = __float_as_uint(v);
    return (u16)((u + 0x7fffu + ((u >> 16) & 1u)) >> 16);
}
// RNE split: hi = RNE(v), lo = RNE(v - hi)
__device__ inline void bsplit(float v, u16& h, u16& l){
    h = f2bf_rne(v);
    float r = v - bf2f(h);
    l = f2bf_rne(r);
}
__device__ inline u32 pack2(u16 a, u16 b){ return (u32)a | ((u32)b << 16); }

// ---------------- CSR build ----------------

__global__ void k_deg(const int* __restrict__ dst, int E, int* __restrict__ deg){
    int i = blockIdx.x*256 + threadIdx.x;
    if (i < E) atomicAdd(&deg[dst[i]], 1);
}

__global__ void k_scanA(const int* __restrict__ deg, int N,
                        int* __restrict__ incl, int* __restrict__ bsums){
    __shared__ int lds[1024];
    int i = blockIdx.x*1024 + threadIdx.x;
    int v = (i < N) ? deg[i] : 0;
    lds[threadIdx.x] = v;
    __syncthreads();
    for (int off = 1; off < 1024; off <<= 1){
        int t = (threadIdx.x >= off) ? lds[threadIdx.x - off] : 0;
        __syncthreads();
        lds[threadIdx.x] += t;
        __syncthreads();
    }
    if (i < N) incl[i] = lds[threadIdx.x];
    if (threadIdx.x == 1023) bsums[blockIdx.x] = lds[1023];
}

__global__ void k_scanB(const int* __restrict__ bsums, int nb, int* __restrict__ ebs){
    __shared__ int lds[1024];
    int t = threadIdx.x;
    int v = (t < nb) ? bsums[t] : 0;
    lds[t] = v;
    __syncthreads();
    for (int off = 1; off < 1024; off <<= 1){
        int u = (t >= off) ? lds[t - off] : 0;
        __syncthreads();
        lds[t] += u;
        __syncthreads();
    }
    ebs[t] = lds[t] - v;   // exclusive
}

__global__ void k_scanC(const int* __restrict__ incl, const int* __restrict__ ebs,
                        int N, int* __restrict__ rowptr){
    int i = blockIdx.x*256 + threadIdx.x;
    if (i < N) rowptr[i+1] = incl[i] + ebs[i >> 10];
    if (i == 0) rowptr[0] = 0;
}

__global__ void k_scatter(const int* __restrict__ src, const int* __restrict__ dst, int E,
                          const int* __restrict__ rowptr, int* __restrict__ fill,
                          int* __restrict__ esrc){
    int i = blockIdx.x*256 + threadIdx.x;
    if (i < E){
        int d = dst[i];
        int pos = rowptr[d] + atomicAdd(&fill[d], 1);
        esrc[pos] = src[i];
    }
}

// ---------------- input / weight conversion ----------------

// x f32 -> single RNE bf16 plane
__global__ void k_xbf(const float* __restrict__ x, u16* __restrict__ xh, int n4){
    int i = blockIdx.x*256 + threadIdx.x;
    if (i >= n4) return;
    float4 v = *(const float4*)&x[(size_t)i*4];
    ushort4 h;
    h.x = f2bf_rne(v.x); h.y = f2bf_rne(v.y);
    h.z = f2bf_rne(v.z); h.w = f2bf_rne(v.w);
    *(ushort4*)&xh[(size_t)i*4] = h;
}

// W [K][256] f32 -> Wt planes [256][K] bf16 hi/lo (optionally BN-scaled per col)
__global__ void k_wsplit(const float* __restrict__ W, u16* __restrict__ wth,
                         u16* __restrict__ wtl, int K,
                         const float* __restrict__ g, const float* __restrict__ vv){
    int i = blockIdx.x*256 + threadIdx.x;
    if (i >= K*256) return;
    int k = i >> 8, c = i & 255;
    float val = W[i];
    if (g) val *= g[c] * rsqrtf(vv[c] + EPS_BN);
    u16 h, l; bsplit(val, h, l);
    wth[c*K + k] = h;
    wtl[c*K + k] = l;
}

// folded BN bias: bias1 = (b1 - mean)*g*rsqrt(var+eps) + beta
__global__ void k_bias1(const float* __restrict__ b1, const float* __restrict__ g,
                        const float* __restrict__ be, const float* __restrict__ m,
                        const float* __restrict__ vv, float* __restrict__ bias1){
    int c = threadIdx.x;
    float s = g[c] * rsqrtf(vv[c] + EPS_BN);
    bias1[c] = (b1[c] - m[c]) * s + be[c];
}

// ---------------- mean aggregation (wave-per-node, 16B/lane gather) ----------------

template<int F>
__global__ __launch_bounds__(128) void k_aggw(const u16* __restrict__ fh,
    const int* __restrict__ rowptr, const int* __restrict__ esrc,
    u16* __restrict__ mh, int N)
{
    const int n = blockIdx.x*2 + (threadIdx.x >> 6);
    if (n >= N) return;
    const int lane = threadIdx.x & 63;
    constexpr int LPR = (F*2)/16;   // lanes per row: F=256 -> 32, F=128 -> 16
    constexpr int EPI = 64/LPR;     // edges in flight: 2 or 4
    const int sub = lane / LPR;
    const int fo  = (lane % LPR) * 8;
    const int s = rowptr[n], e = rowptr[n+1];

    float a[8] = {};
    for (int j = s + sub; j < e; j += EPI){
        uint4 v = *(const uint4*)(fh + (size_t)esrc[j]*F + fo);
        a[0] += __uint_as_float(v.x << 16); a[1] += __uint_as_float(v.x & 0xffff0000u);
        a[2] += __uint_as_float(v.y << 16); a[3] += __uint_as_float(v.y & 0xffff0000u);
        a[4] += __uint_as_float(v.z << 16); a[5] += __uint_as_float(v.z & 0xffff0000u);
        a[6] += __uint_as_float(v.w << 16); a[7] += __uint_as_float(v.w & 0xffff0000u);
    }
    #pragma unroll
    for (int k = 0; k < 8; ++k){
        if constexpr (EPI == 4) a[k] += __shfl_xor(a[k], 16, 64);
        a[k] += __shfl_xor(a[k], 32, 64);
    }
    if (sub == 0){
        const float rc = 1.f / fmaxf((float)(e - s), 1.f);
        uint4 o;
        o.x = pack2(f2bf_rne(a[0]*rc), f2bf_rne(a[1]*rc));
        o.y = pack2(f2bf_rne(a[2]*rc), f2bf_rne(a[3]*rc));
        o.z = pack2(f2bf_rne(a[4]*rc), f2bf_rne(a[5]*rc));
        o.w = pack2(f2bf_rne(a[6]*rc), f2bf_rne(a[7]*rc));
        *(uint4*)(mh + (size_t)n*F + fo) = o;
    }
}

// ---------------- bf16 MFMA dual GEMM, 128x256 tile, 8 waves, fused epilogue ----
// out = A1@W1 + A2@W2 + bias [+ReLU] [+row-L2-norm]. K concat: NKB1+NKB2 x32.
// A: single bf16 plane [N][sA]. B: Wt hi/lo planes [256][sB]. Tile 128 rows x
// 256 cols (ALL cols), 512 thr = 8 waves (2 row x 4 col of 64x64).
// LDS/buf: A[128][32] (512 uint4) + Bhi (1024) + Blo (1024) = 2560 uint4; x2 dbuf
// = 80 KB -> 2 blocks/CU. 16B-chunk swizzle slot = r*4 + (chunk ^ (r&3)).
// Loads 2 K-steps ahead, LDS write 1 ahead, ONE barrier per step.
// Epilogue: values -> LDS (padded rows) -> coalesced uint4 global stores.

template<int NKB1, int NKB2, bool RELU, bool WRITE_H, bool L2N>
__global__ __launch_bounds__(512, 4) void k_gemm(
    const u16* __restrict__ A1, int sa1,
    const u16* __restrict__ A2, int sa2,
    const u16* __restrict__ B1h, const u16* __restrict__ B1l, int sb1,
    const u16* __restrict__ B2h, const u16* __restrict__ B2l, int sb2,
    const float* __restrict__ bias,
    int N, float* __restrict__ outf, u16* __restrict__ outh)
{
    constexpr int BUFSZ = 2560;           // uint4 per buffer
    __shared__ uint4 L[2*BUFSZ];          // 81920 B

    const int t    = threadIdx.x;
    const int wave = t >> 6, lane = t & 63;
    const int wr   = (wave >> 2) * 64;    // 2 row-groups
    const int wc   = (wave &  3) * 64;    // 4 col-groups
    const int m0   = blockIdx.x * 128;

    f32x4 acc[4][4] = {};

    // A staging: 1 chunk/thread
    const int aslot = (t >> 2)*4 + ((t & 3) ^ ((t >> 2) & 3));
    const size_t arow = (size_t)min(m0 + (t >> 2), N-1);
    const int ach8 = (t & 3) * 8;
    // B staging: 4 chunks/thread
    int bslot[4], bcol[4], bch8[4], bplane[4];
    #pragma unroll
    for (int it = 0; it < 4; ++it){
        int idx = t + it*512;          // 0..2047
        int pl = idx >> 10;            // 0 hi, 1 lo
        int ci = idx & 1023;
        int col = ci >> 2, ch = ci & 3;
        bplane[it] = pl; bcol[it] = col; bch8[it] = ch*8;
        bslot[it] = 512 + pl*1024 + col*4 + (ch ^ (col & 3));
    }

    uint4 sA0, sB[4];
    auto LOADK = [&](int kb){
        const u16 *pA, *pBh, *pBl; int sA, sBs, k0;
        if (kb < NKB1){ pA=A1; sA=sa1; pBh=B1h; pBl=B1l; sBs=sb1; k0 = kb*32; }
        else          { pA=A2; sA=sa2; pBh=B2h; pBl=B2l; sBs=sb2; k0 = (kb-NKB1)*32; }
        sA0 = *(const uint4*)(pA + arow*sA + k0 + ach8);
        #pragma unroll
        for (int it = 0; it < 4; ++it){
            const u16* pB = bplane[it] ? pBl : pBh;
            sB[it] = *(const uint4*)(pB + (size_t)bcol[it]*sBs + k0 + bch8[it]);
        }
    };
    auto STOREK = [&](int buf){
        uint4* Lb = &L[buf*BUFSZ];
        Lb[aslot] = sA0;
        #pragma unroll
        for (int it = 0; it < 4; ++it) Lb[bslot[it]] = sB[it];
    };

    constexpr int NKB = NKB1 + NKB2;
    LOADK(0);
    STOREK(0);
    LOADK(1);
    __syncthreads();

    const int cl = lane & 15;
    const int cg = lane >> 4;

    #pragma unroll 2
    for (int kb = 0; kb < NKB; ++kb){
        const int cur = kb & 1;
        uint4* Lb = &L[cur*BUFSZ];
        if (kb + 1 < NKB) STOREK(cur ^ 1);
        if (kb + 2 < NKB) LOADK(kb + 2);

        short8 bh[4], bl[4];
        #pragma unroll
        for (int n = 0; n < 4; ++n){
            int col  = wc + n*16 + cl;
            int so   = col*4 + (cg ^ (col & 3));
            bh[n] = *(const short8*)&Lb[512 + so];
            bl[n] = *(const short8*)&Lb[1536 + so];
        }
        #pragma unroll
        for (int m = 0; m < 4; ++m){
            int row = wr + m*16 + cl;
            int so  = row*4 + (cg ^ (row & 3));
            short8 ah = *(const short8*)&Lb[so];
            #pragma unroll
            for (int n = 0; n < 4; ++n){
                acc[m][n] = __builtin_amdgcn_mfma_f32_16x16x32_bf16(ah, bh[n], acc[m][n], 0,0,0);
                acc[m][n] = __builtin_amdgcn_mfma_f32_16x16x32_bf16(ah, bl[n], acc[m][n], 0,0,0);
            }
        }
        __syncthreads();
    }

    // ---- epilogue. C/D layout: col = lane&15 (cl), row = rg*4 + reg ----
    const int rg = lane >> 4;

    if constexpr (WRITE_H){
        // bias + ReLU -> bf16 -> LDS [128][264] u16 (padded) -> coalesced stores
        u16* Ls = (u16*)L;
        #pragma unroll
        for (int n = 0; n < 4; ++n){
            int col = wc + n*16 + cl;
            float bv = bias[col];
            #pragma unroll
            for (int m = 0; m < 4; ++m){
                #pragma unroll
                for (int i = 0; i < 4; ++i){
                    float v = acc[m][n][i] + bv;
                    if constexpr (RELU) v = fmaxf(v, 0.f);
                    int lr = wr + m*16 + rg*4 + i;
                    Ls[lr*264 + col] = f2bf_rne(v);
                }
            }
        }
        __syncthreads();
        #pragma unroll
        for (int j = 0; j < 8; ++j){
            int cid = j*512 + t;          // 0..4095
            int lr = cid >> 5, c16 = cid & 31;
            int grow = m0 + lr;
            if (grow < N){
                uint4 vv = *(const uint4*)((const char*)L + lr*528 + c16*16);
                *(uint4*)(outh + (size_t)grow*256 + c16*8) = vv;
            }
        }
    } else {
        // bias add (+ optional fused row L2 norm) -> f32 -> LDS -> coalesced stores
        float rn[4][4];
        if constexpr (L2N){
            float* smp = (float*)L + 19968;   // bytes 79872..81920: sm[4][128]
            float ps[4][4] = {};
            #pragma unroll
            for (int n = 0; n < 4; ++n){
                int col = wc + n*16 + cl;
                float bv = bias[col];
                #pragma unroll
                for (int m = 0; m < 4; ++m){
                    #pragma unroll
                    for (int i = 0; i < 4; ++i){
                        float v = acc[m][n][i] + bv;
                        acc[m][n][i] = v;
                        ps[m][i] += v*v;
                    }
                }
            }
            #pragma unroll
            for (int mask = 1; mask <= 8; mask <<= 1){
                #pragma unroll
                for (int m = 0; m < 4; ++m)
                    #pragma unroll
                    for (int i = 0; i < 4; ++i)
                        ps[m][i] += __shfl_xor(ps[m][i], mask, 64);
            }
            if (cl == 0){
                #pragma unroll
                for (int m = 0; m < 4; ++m)
                    #pragma unroll
                    for (int i = 0; i < 4; ++i)
                        smp[(wave & 3)*128 + wr + m*16 + rg*4 + i] = ps[m][i];
            }
            __syncthreads();
            #pragma unroll
            for (int m = 0; m < 4; ++m){
                #pragma unroll
                for (int i = 0; i < 4; ++i){
                    int lr = wr + m*16 + rg*4 + i;
                    float s = smp[lr] + smp[128+lr] + smp[256+lr] + smp[384+lr];
                    rn[m][i] = 1.f / fmaxf(sqrtf(s), EPS_L2);
                }
            }
        } else {
            #pragma unroll
            for (int n = 0; n < 4; ++n){
                int col = wc + n*16 + cl;
                float bv = bias[col];
                #pragma unroll
                for (int m = 0; m < 4; ++m)
                    #pragma unroll
                    for (int i = 0; i < 4; ++i)
                        acc[m][n][i] += bv;
            }
            #pragma unroll
            for (int m = 0; m < 4; ++m)
                #pragma unroll
                for (int i = 0; i < 4; ++i) rn[m][i] = 1.f;
        }
        // two half-tile passes through LDS [64][260] f32 (padded)
        float* Lf = (float*)L;
        #pragma unroll
        for (int p = 0; p < 2; ++p){
            if ((wave >> 2) == p){
                #pragma unroll
                for (int n = 0; n < 4; ++n){
                    int col = wc + n*16 + cl;
                    #pragma unroll
                    for (int m = 0; m < 4; ++m)
                        #pragma unroll
                        for (int i = 0; i < 4; ++i){
                            int lr = m*16 + rg*4 + i;
                            Lf[lr*260 + col] = acc[m][n][i] * rn[m][i];
                        }
                }
            }
            __syncthreads();
            #pragma unroll
            for (int j = 0; j < 8; ++j){
                int cid = j*512 + t;      // 0..4095
                int lr = cid >> 6, c = cid & 63;
                int grow = m0 + p*64 + lr;
                if (grow < N){
                    uint4 vv = *(const uint4*)((const char*)L + lr*1040 + c*16);
                    *(uint4*)(outf + (size_t)grow*256 + c*4) = vv;
                }
            }
            __syncthreads();
        }
    }
}

// ---------------- launch ----------------

extern "C" void kernel_launch(void* const* d_in, const int* in_sizes, int n_in,
                              void* d_out, int out_size, void* d_ws, size_t ws_size,
                              hipStream_t stream){
    const float* x   = (const float*)d_in[0];
    const int*   ei  = (const int*)  d_in[1];
    const float* W1l = (const float*)d_in[2];
    const float* b1l = (const float*)d_in[3];
    const float* W1r = (const float*)d_in[4];
    const float* bng = (const float*)d_in[5];
    const float* bnb = (const float*)d_in[6];
    const float* bnm = (const float*)d_in[7];
    const float* bnv = (const float*)d_in[8];
    const float* W2l = (const float*)d_in[9];
    const float* b2l = (const float*)d_in[10];
    const float* W2r = (const float*)d_in[11];
    float* out = (float*)d_out;

    const int N = in_sizes[0] / IN_F;
    const int E = in_sizes[1] / 2;
    const int* src = ei;
    const int* dst = ei + E;

    char* w = (char*)d_ws;
    auto alloc = [&](size_t bytes)->char*{
        char* p = w; w += (bytes + 255) & ~(size_t)255; return p;
    };
    int* deg    = (int*)alloc((size_t)N*4);
    int* fill   = (int*)alloc((size_t)N*4);
    int* incl   = (int*)alloc((size_t)N*4);
    int* rowptr = (int*)alloc((size_t)(N+1)*4);
    int* bsums  = (int*)alloc(1024*4);
    int* ebs    = (int*)alloc(1024*4);
    int* esrc   = (int*)alloc((size_t)E*4);
    // region R: xh + m1 contiguous (N*128 u16 each, exact 256-multiples);
    // m2 (N*256 u16) aliases the combined span after x/m1 are dead.
    u16* xh  = (u16*)alloc((size_t)N*IN_F*2);
    u16* m1  = (u16*)alloc((size_t)N*IN_F*2);
    u16* hh  = (u16*)alloc((size_t)N*HID*2);
    u16* w1lh = (u16*)alloc((size_t)IN_F*256*2);
    u16* w1ll = (u16*)alloc((size_t)IN_F*256*2);
    u16* w1rh = (u16*)alloc((size_t)IN_F*256*2);
    u16* w1rl = (u16*)alloc((size_t)IN_F*256*2);
    u16* w2lh = (u16*)alloc((size_t)HID*256*2);
    u16* w2ll = (u16*)alloc((size_t)HID*256*2);
    u16* w2rh = (u16*)alloc((size_t)HID*256*2);
    u16* w2rl = (u16*)alloc((size_t)HID*256*2);
    float* bias1 = (float*)alloc(256*4);
    u16* m2 = xh;   // N*256 u16 spans xh..m1 exactly

    hipMemsetAsync(deg,  0, (size_t)N*4, stream);
    hipMemsetAsync(fill, 0, (size_t)N*4, stream);

    const int eb = (E + 255) / 256;
    const int nb = (N + 1023) / 1024;

    k_deg    <<<eb, 256, 0, stream>>>(dst, E, deg);
    k_scanA  <<<nb, 1024, 0, stream>>>(deg, N, incl, bsums);
    k_scanB  <<<1, 1024, 0, stream>>>(bsums, nb, ebs);
    k_scanC  <<<(N+255)/256, 256, 0, stream>>>(incl, ebs, N, rowptr);
    k_scatter<<<eb, 256, 0, stream>>>(src, dst, E, rowptr, fill, esrc);

    // conversions (W1 planes BN-scaled; bias1 folded)
    k_xbf<<<((N*IN_F/4)+255)/256, 256, 0, stream>>>(x, xh, N*IN_F/4);
    k_wsplit<<<(IN_F*256+255)/256, 256, 0, stream>>>(W1l, w1lh, w1ll, IN_F, bng, bnv);
    k_wsplit<<<(IN_F*256+255)/256, 256, 0, stream>>>(W1r, w1rh, w1rl, IN_F, bng, bnv);
    k_wsplit<<<(HID*256+255)/256, 256, 0, stream>>>(W2l, w2lh, w2ll, HID, nullptr, nullptr);
    k_wsplit<<<(HID*256+255)/256, 256, 0, stream>>>(W2r, w2rh, w2rl, HID, nullptr, nullptr);
    k_bias1<<<1, 256, 0, stream>>>(b1l, bng, bnb, bnm, bnv, bias1);

    const int nwg = (N + 127) / 128;

    // layer 1: h = relu(mean1@W1l' + x@W1r' + bias1) -> bf16
    k_aggw<IN_F><<<(N+1)/2, 128, 0, stream>>>(xh, rowptr, esrc, m1, N);
    k_gemm<4, 4, true, true, false><<<nwg, 512, 0, stream>>>(
        m1, IN_F, xh, IN_F,
        w1lh, w1ll, IN_F, w1rh, w1rl, IN_F,
        bias1, N, nullptr, hh);

    // layer 2: out = l2norm(mean2@W2l + h@W2r + b2l)
    k_aggw<HID><<<(N+1)/2, 128, 0, stream>>>(hh, rowptr, esrc, m2, N);
    k_gemm<8, 8, false, false, true><<<nwg, 512, 0, stream>>>(
        m2, HID, hh, HID,
        w2lh, w2ll, HID, w2rh, w2rl, HID,
        b2l, N, out, nullptr);
}

// Round 10
// 506.425 us; speedup vs baseline: 1.2030x; 1.2030x over previous
//
#include <hip/hip_runtime.h>
#include <cstdint>
#include <cstddef>

typedef unsigned short u16;
typedef unsigned int u32;
typedef __attribute__((ext_vector_type(8))) short short8;
typedef __attribute__((ext_vector_type(4))) float f32x4;

static constexpr int IN_F = 128;
static constexpr int HID  = 256;
#define EPS_BN 1e-5f
#define EPS_L2 1e-12f

__device__ inline float bf2f(u16 a){ return __uint_as_float((unsigned)a << 16); }
__device__ inline u16 f2bf_rne(float v){
    unsigned u = __float_as_uint(v);
    return (u16)((u + 0x7fffu + ((u >> 16) & 1u)) >> 16);
}
// RNE split: hi = RNE(v), lo = RNE(v - hi)
__device__ inline void bsplit(float v, u16& h, u16& l){
    h = f2bf_rne(v);
    float r = v - bf2f(h);
    l = f2bf_rne(r);
}
__device__ inline u32 pack2(u16 a, u16 b){ return (u32)a | ((u32)b << 16); }

// ---------------- CSR build ----------------

__global__ void k_deg(const int* __restrict__ dst, int E, int* __restrict__ deg){
    int i = blockIdx.x*256 + threadIdx.x;
    if (i < E) atomicAdd(&deg[dst[i]], 1);
}

__global__ void k_scanA(const int* __restrict__ deg, int N,
                        int* __restrict__ incl, int* __restrict__ bsums){
    __shared__ int lds[1024];
    int i = blockIdx.x*1024 + threadIdx.x;
    int v = (i < N) ? deg[i] : 0;
    lds[threadIdx.x] = v;
    __syncthreads();
    for (int off = 1; off < 1024; off <<= 1){
        int t = (threadIdx.x >= off) ? lds[threadIdx.x - off] : 0;
        __syncthreads();
        lds[threadIdx.x] += t;
        __syncthreads();
    }
    if (i < N) incl[i] = lds[threadIdx.x];
    if (threadIdx.x == 1023) bsums[blockIdx.x] = lds[1023];
}

__global__ void k_scanB(const int* __restrict__ bsums, int nb, int* __restrict__ ebs){
    __shared__ int lds[1024];
    int t = threadIdx.x;
    int v = (t < nb) ? bsums[t] : 0;
    lds[t] = v;
    __syncthreads();
    for (int off = 1; off < 1024; off <<= 1){
        int u = (t >= off) ? lds[t - off] : 0;
        __syncthreads();
        lds[t] += u;
        __syncthreads();
    }
    ebs[t] = lds[t] - v;   // exclusive
}

__global__ void k_scanC(const int* __restrict__ incl, const int* __restrict__ ebs,
                        int N, int* __restrict__ rowptr){
    int i = blockIdx.x*256 + threadIdx.x;
    if (i < N) rowptr[i+1] = incl[i] + ebs[i >> 10];
    if (i == 0) rowptr[0] = 0;
}

__global__ void k_scatter(const int* __restrict__ src, const int* __restrict__ dst, int E,
                          const int* __restrict__ rowptr, int* __restrict__ fill,
                          int* __restrict__ esrc){
    int i = blockIdx.x*256 + threadIdx.x;
    if (i < E){
        int d = dst[i];
        int pos = rowptr[d] + atomicAdd(&fill[d], 1);
        esrc[pos] = src[i];
    }
}

// ---------------- input / weight conversion ----------------

// x f32 -> single RNE bf16 plane
__global__ void k_xbf(const float* __restrict__ x, u16* __restrict__ xh, int n4){
    int i = blockIdx.x*256 + threadIdx.x;
    if (i >= n4) return;
    float4 v = *(const float4*)&x[(size_t)i*4];
    ushort4 h;
    h.x = f2bf_rne(v.x); h.y = f2bf_rne(v.y);
    h.z = f2bf_rne(v.z); h.w = f2bf_rne(v.w);
    *(ushort4*)&xh[(size_t)i*4] = h;
}

// W [K][256] f32 -> Wt planes [256][K] bf16 hi/lo (optionally BN-scaled per col)
__global__ void k_wsplit(const float* __restrict__ W, u16* __restrict__ wth,
                         u16* __restrict__ wtl, int K,
                         const float* __restrict__ g, const float* __restrict__ vv){
    int i = blockIdx.x*256 + threadIdx.x;
    if (i >= K*256) return;
    int k = i >> 8, c = i & 255;
    float val = W[i];
    if (g) val *= g[c] * rsqrtf(vv[c] + EPS_BN);
    u16 h, l; bsplit(val, h, l);
    wth[c*K + k] = h;
    wtl[c*K + k] = l;
}

// folded BN bias: bias1 = (b1 - mean)*g*rsqrt(var+eps) + beta
__global__ void k_bias1(const float* __restrict__ b1, const float* __restrict__ g,
                        const float* __restrict__ be, const float* __restrict__ m,
                        const float* __restrict__ vv, float* __restrict__ bias1){
    int c = threadIdx.x;
    float s = g[c] * rsqrtf(vv[c] + EPS_BN);
    bias1[c] = (b1[c] - m[c]) * s + be[c];
}

// ---------------- mean aggregation (wave-per-node, 16B/lane gather) ----------------

template<int F>
__global__ __launch_bounds__(128) void k_aggw(const u16* __restrict__ fh,
    const int* __restrict__ rowptr, const int* __restrict__ esrc,
    u16* __restrict__ mh, int N)
{
    const int n = blockIdx.x*2 + (threadIdx.x >> 6);
    if (n >= N) return;
    const int lane = threadIdx.x & 63;
    constexpr int LPR = (F*2)/16;   // lanes per row: F=256 -> 32, F=128 -> 16
    constexpr int EPI = 64/LPR;     // edges in flight: 2 or 4
    const int sub = lane / LPR;
    const int fo  = (lane % LPR) * 8;
    const int s = rowptr[n], e = rowptr[n+1];

    float a[8] = {};
    for (int j = s + sub; j < e; j += EPI){
        uint4 v = *(const uint4*)(fh + (size_t)esrc[j]*F + fo);
        a[0] += __uint_as_float(v.x << 16); a[1] += __uint_as_float(v.x & 0xffff0000u);
        a[2] += __uint_as_float(v.y << 16); a[3] += __uint_as_float(v.y & 0xffff0000u);
        a[4] += __uint_as_float(v.z << 16); a[5] += __uint_as_float(v.z & 0xffff0000u);
        a[6] += __uint_as_float(v.w << 16); a[7] += __uint_as_float(v.w & 0xffff0000u);
    }
    #pragma unroll
    for (int k = 0; k < 8; ++k){
        if constexpr (EPI == 4) a[k] += __shfl_xor(a[k], 16, 64);
        a[k] += __shfl_xor(a[k], 32, 64);
    }
    if (sub == 0){
        const float rc = 1.f / fmaxf((float)(e - s), 1.f);
        uint4 o;
        o.x = pack2(f2bf_rne(a[0]*rc), f2bf_rne(a[1]*rc));
        o.y = pack2(f2bf_rne(a[2]*rc), f2bf_rne(a[3]*rc));
        o.z = pack2(f2bf_rne(a[4]*rc), f2bf_rne(a[5]*rc));
        o.w = pack2(f2bf_rne(a[6]*rc), f2bf_rne(a[7]*rc));
        *(uint4*)(mh + (size_t)n*F + fo) = o;
    }
}

// ---------------- bf16 MFMA dual GEMM (round-8 geometry + LDS-staged stores) ----
// out = A1@W1 + A2@W2 + bias [+ReLU]. K concat: NKB1+NKB2 blocks of 32 k.
// A: single bf16 plane. B: Wt hi/lo planes. Tile 128x128, 256 thr = 4 waves
// (2x2 of 64x64), mfma_f32_16x16x32_bf16. LDS slot = row*4 + (chunk ^ (row&3)).
// Loads 2 K-steps ahead, LDS write 1 ahead, ONE barrier/step. 1-D grid +
// bijective XCD swizzle. Epilogue: acc -> LDS (padded) -> coalesced uint4 stores.

template<int NKB1, int NKB2, bool RELU, bool WRITE_H>
__global__ __launch_bounds__(256, 3) void k_gemm(
    const u16* __restrict__ A1, int sa1,
    const u16* __restrict__ A2, int sa2,
    const u16* __restrict__ B1h, const u16* __restrict__ B1l, int sb1,
    const u16* __restrict__ B2h, const u16* __restrict__ B2l, int sb2,
    const float* __restrict__ bias,
    int N, float* __restrict__ outf, u16* __restrict__ outh)
{
    constexpr int ABUF  = 512;            // uint4 for A tile
    constexpr int BUFSZ = ABUF + 1024;    // + B hi/lo
    __shared__ uint4 L[2*BUFSZ];          // 49152 B -> 3 blocks/CU

    // bijective XCD swizzle (8 XCDs)
    const int nwg = gridDim.x;
    const int q = nwg >> 3, r = nwg & 7;
    const int orig = blockIdx.x;
    const int xcd = orig & 7, pos = orig >> 3;
    const int wgid = (xcd < r ? xcd*(q+1) : r*(q+1) + (xcd-r)*q) + pos;
    const int c0 = (wgid & 1) * 128;
    const int m0 = (wgid >> 1) * 128;

    const int t    = threadIdx.x;
    const int wave = t >> 6, lane = t & 63;
    const int wr   = (wave >> 1) * 64;
    const int wc   = (wave &  1) * 64;

    f32x4 acc[4][4] = {};

    const int r0 = t >> 2,        cc0 = t & 3;
    const int r1 = (t+256) >> 2,  cc1 = (t+256) & 3;
    const int slot0 = r0*4 + (cc0 ^ (r0 & 3));
    const int slot1 = r1*4 + (cc1 ^ (r1 & 3));
    const int ar0 = min(m0 + r0, N-1);
    const int ar1 = min(m0 + r1, N-1);
    const int br0 = c0 + r0, br1 = c0 + r1;

    uint4 sA0, sA1, sBh0, sBh1, sBl0, sBl1;

    auto LOADK = [&](int kb){
        const u16 *pA, *pBh, *pBl; int sA, sB, k0;
        if (kb < NKB1){ pA=A1; sA=sa1; pBh=B1h; pBl=B1l; sB=sb1; k0 = kb*32; }
        else          { pA=A2; sA=sa2; pBh=B2h; pBl=B2l; sB=sb2; k0 = (kb-NKB1)*32; }
        sA0  = *(const uint4*)(pA  + (size_t)ar0*sA + k0 + cc0*8);
        sA1  = *(const uint4*)(pA  + (size_t)ar1*sA + k0 + cc1*8);
        sBh0 = *(const uint4*)(pBh + (size_t)br0*sB + k0 + cc0*8);
        sBh1 = *(const uint4*)(pBh + (size_t)br1*sB + k0 + cc1*8);
        sBl0 = *(const uint4*)(pBl + (size_t)br0*sB + k0 + cc0*8);
        sBl1 = *(const uint4*)(pBl + (size_t)br1*sB + k0 + cc1*8);
    };
    auto STOREK = [&](int buf){
        uint4* Lb = &L[buf*BUFSZ];
        Lb[slot0] = sA0;  Lb[slot1] = sA1;
        Lb[ABUF+slot0]     = sBh0;  Lb[ABUF+slot1]     = sBh1;
        Lb[ABUF+512+slot0] = sBl0;  Lb[ABUF+512+slot1] = sBl1;
    };

    constexpr int NKB = NKB1 + NKB2;
    LOADK(0);
    STOREK(0);
    LOADK(1);
    __syncthreads();

    const int cl = lane & 15;
    const int cg = lane >> 4;

    #pragma unroll 2
    for (int kb = 0; kb < NKB; ++kb){
        const int cur = kb & 1;
        uint4* Lb = &L[cur*BUFSZ];
        if (kb + 1 < NKB) STOREK(cur ^ 1);   // data(kb+1) -> other buffer
        if (kb + 2 < NKB) LOADK(kb + 2);     // issue loads 2 ahead

        short8 bh[4], bl[4];
        #pragma unroll
        for (int n = 0; n < 4; ++n){
            int col  = wc + n*16 + cl;
            int slot = col*4 + (cg ^ (col & 3));
            bh[n] = *(const short8*)&Lb[ABUF+slot];
            bl[n] = *(const short8*)&Lb[ABUF+512+slot];
        }
        #pragma unroll
        for (int m = 0; m < 4; ++m){
            int row  = wr + m*16 + cl;
            int slot = row*4 + (cg ^ (row & 3));
            short8 ah = *(const short8*)&Lb[slot];
            #pragma unroll
            for (int n = 0; n < 4; ++n){
                acc[m][n] = __builtin_amdgcn_mfma_f32_16x16x32_bf16(ah, bh[n], acc[m][n], 0,0,0);
                acc[m][n] = __builtin_amdgcn_mfma_f32_16x16x32_bf16(ah, bl[n], acc[m][n], 0,0,0);
            }
        }
        __syncthreads();
    }
    // main loop ends with a barrier: L is free for epilogue staging.

    // ---- epilogue. C/D layout: col = lane&15 (cl), row = (lane>>4)*4 + reg ----
    const int rg = lane >> 4;

    if constexpr (WRITE_H){
        // bias+ReLU -> bf16 -> LDS [128][136] u16 (272B stride) -> coalesced stores
        u16* Ls = (u16*)L;
        #pragma unroll
        for (int n = 0; n < 4; ++n){
            int col = wc + n*16 + cl;
            float bv = bias[c0 + col];
            #pragma unroll
            for (int m = 0; m < 4; ++m){
                #pragma unroll
                for (int i = 0; i < 4; ++i){
                    float v = acc[m][n][i] + bv;
                    if constexpr (RELU) v = fmaxf(v, 0.f);
                    Ls[(wr + m*16 + rg*4 + i)*136 + col] = f2bf_rne(v);
                }
            }
        }
        __syncthreads();
        #pragma unroll
        for (int j = 0; j < 8; ++j){
            int cid = j*256 + t;          // 0..2047 chunks (128 rows x 16)
            int lr = cid >> 4, c16 = cid & 15;
            int grow = m0 + lr;
            if (grow < N){
                uint4 vv = *(const uint4*)((const char*)L + lr*272 + c16*16);
                *(uint4*)(outh + (size_t)grow*256 + c0 + c16*8) = vv;
            }
        }
    } else {
        // bias -> f32 -> LDS [64][132] (528B stride), two half-tile passes
        float* Lf = (float*)L;
        #pragma unroll
        for (int p = 0; p < 2; ++p){
            if ((wave >> 1) == p){
                #pragma unroll
                for (int n = 0; n < 4; ++n){
                    int col = wc + n*16 + cl;
                    float bv = bias[c0 + col];
                    #pragma unroll
                    for (int m = 0; m < 4; ++m)
                        #pragma unroll
                        for (int i = 0; i < 4; ++i)
                            Lf[(m*16 + rg*4 + i)*132 + col] = acc[m][n][i] + bv;
                }
            }
            __syncthreads();
            #pragma unroll
            for (int j = 0; j < 8; ++j){
                int cid = j*256 + t;      // 0..2047 chunks (64 rows x 32)
                int lr = cid >> 5, c = cid & 31;
                int grow = m0 + p*64 + lr;
                if (grow < N){
                    uint4 vv = *(const uint4*)((const char*)L + lr*528 + c*16);
                    *(uint4*)(outf + (size_t)grow*256 + c0 + c*4) = vv;
                }
            }
            __syncthreads();
        }
    }
}

// ---------------- in-place row L2 normalize ----------------

__global__ __launch_bounds__(256) void k_l2norm(float* __restrict__ out, int N){
    int n = blockIdx.x;
    int t = threadIdx.x;
    float v = out[(size_t)n*256 + t];
    float s = v*v;
    #pragma unroll
    for (int off = 32; off; off >>= 1) s += __shfl_xor(s, off, 64);
    __shared__ float ws[4];
    if ((t & 63) == 0) ws[t >> 6] = s;
    __syncthreads();
    s = ws[0] + ws[1] + ws[2] + ws[3];
    float nrm = fmaxf(sqrtf(s), EPS_L2);
    out[(size_t)n*256 + t] = v / nrm;
}

// ---------------- launch ----------------

extern "C" void kernel_launch(void* const* d_in, const int* in_sizes, int n_in,
                              void* d_out, int out_size, void* d_ws, size_t ws_size,
                              hipStream_t stream){
    const float* x   = (const float*)d_in[0];
    const int*   ei  = (const int*)  d_in[1];
    const float* W1l = (const float*)d_in[2];
    const float* b1l = (const float*)d_in[3];
    const float* W1r = (const float*)d_in[4];
    const float* bng = (const float*)d_in[5];
    const float* bnb = (const float*)d_in[6];
    const float* bnm = (const float*)d_in[7];
    const float* bnv = (const float*)d_in[8];
    const float* W2l = (const float*)d_in[9];
    const float* b2l = (const float*)d_in[10];
    const float* W2r = (const float*)d_in[11];
    float* out = (float*)d_out;

    const int N = in_sizes[0] / IN_F;
    const int E = in_sizes[1] / 2;
    const int* src = ei;
    const int* dst = ei + E;

    char* w = (char*)d_ws;
    auto alloc = [&](size_t bytes)->char*{
        char* p = w; w += (bytes + 255) & ~(size_t)255; return p;
    };
    int* deg    = (int*)alloc((size_t)N*4);
    int* fill   = (int*)alloc((size_t)N*4);
    int* incl   = (int*)alloc((size_t)N*4);
    int* rowptr = (int*)alloc((size_t)(N+1)*4);
    int* bsums  = (int*)alloc(1024*4);
    int* ebs    = (int*)alloc(1024*4);
    int* esrc   = (int*)alloc((size_t)E*4);
    // region R: xh + m1 contiguous (N*128 u16 each, exact 256-multiples);
    // m2 (N*256 u16) aliases the combined span after x/m1 are dead.
    u16* xh  = (u16*)alloc((size_t)N*IN_F*2);
    u16* m1  = (u16*)alloc((size_t)N*IN_F*2);
    u16* hh  = (u16*)alloc((size_t)N*HID*2);
    u16* w1lh = (u16*)alloc((size_t)IN_F*256*2);
    u16* w1ll = (u16*)alloc((size_t)IN_F*256*2);
    u16* w1rh = (u16*)alloc((size_t)IN_F*256*2);
    u16* w1rl = (u16*)alloc((size_t)IN_F*256*2);
    u16* w2lh = (u16*)alloc((size_t)HID*256*2);
    u16* w2ll = (u16*)alloc((size_t)HID*256*2);
    u16* w2rh = (u16*)alloc((size_t)HID*256*2);
    u16* w2rl = (u16*)alloc((size_t)HID*256*2);
    float* bias1 = (float*)alloc(256*4);
    u16* m2 = xh;   // N*256 u16 spans xh..m1 exactly

    hipMemsetAsync(deg,  0, (size_t)N*4, stream);
    hipMemsetAsync(fill, 0, (size_t)N*4, stream);

    const int eb = (E + 255) / 256;
    const int nb = (N + 1023) / 1024;

    k_deg    <<<eb, 256, 0, stream>>>(dst, E, deg);
    k_scanA  <<<nb, 1024, 0, stream>>>(deg, N, incl, bsums);
    k_scanB  <<<1, 1024, 0, stream>>>(bsums, nb, ebs);
    k_scanC  <<<(N+255)/256, 256, 0, stream>>>(incl, ebs, N, rowptr);
    k_scatter<<<eb, 256, 0, stream>>>(src, dst, E, rowptr, fill, esrc);

    // conversions (W1 planes BN-scaled; bias1 folded)
    k_xbf<<<((N*IN_F/4)+255)/256, 256, 0, stream>>>(x, xh, N*IN_F/4);
    k_wsplit<<<(IN_F*256+255)/256, 256, 0, stream>>>(W1l, w1lh, w1ll, IN_F, bng, bnv);
    k_wsplit<<<(IN_F*256+255)/256, 256, 0, stream>>>(W1r, w1rh, w1rl, IN_F, bng, bnv);
    k_wsplit<<<(HID*256+255)/256, 256, 0, stream>>>(W2l, w2lh, w2ll, HID, nullptr, nullptr);
    k_wsplit<<<(HID*256+255)/256, 256, 0, stream>>>(W2r, w2rh, w2rl, HID, nullptr, nullptr);
    k_bias1<<<1, 256, 0, stream>>>(b1l, bng, bnb, bnm, bnv, bias1);

    const int nrt = (N + 127) / 128;      // row tiles
    const int nwg = nrt * 2;              // x2 column tiles, flattened

    // layer 1: h = relu(mean1@W1l' + x@W1r' + bias1) -> bf16
    k_aggw<IN_F><<<(N+1)/2, 128, 0, stream>>>(xh, rowptr, esrc, m1, N);
    k_gemm<4, 4, true, true><<<nwg, 256, 0, stream>>>(
        m1, IN_F, xh, IN_F,
        w1lh, w1ll, IN_F, w1rh, w1rl, IN_F,
        bias1, N, nullptr, hh);

    // layer 2: out = mean2@W2l + h@W2r + b2l, then row L2 norm
    k_aggw<HID><<<(N+1)/2, 128, 0, stream>>>(hh, rowptr, esrc, m2, N);
    k_gemm<8, 8, false, false><<<nwg, 256, 0, stream>>>(
        m2, HID, hh, HID,
        w2lh, w2ll, HID, w2rh, w2rl, HID,
        b2l, N, out, nullptr);

    k_l2norm<<<N, 256, 0, stream>>>(out, N);
}